// Round 1
// baseline (3265.201 us; speedup 1.0000x reference)
//
#include <hip/hip_runtime.h>

#define EPSV 1e-5f
#define STATS_BLOCKS 512

// ---------------- degree / normalization ----------------
__global__ void k_deg(const int* __restrict__ dst, int E, int* __restrict__ degc){
  int i = blockIdx.x*blockDim.x + threadIdx.x;
  if(i < E) atomicAdd(&degc[dst[i]], 1);
}

__global__ void k_dis(const int* __restrict__ degc, int N, float* __restrict__ dis){
  int i = blockIdx.x*blockDim.x + threadIdx.x;
  if(i < N) dis[i] = rsqrtf((float)degc[i] + 1.0f);
}

// ---------------- layer-1 GEMM: [N,32] @ [32,16] -> [N,16] ----------------
__global__ __launch_bounds__(256) void k_gemm1(const float* __restrict__ x,
                                               const float* __restrict__ W,
                                               int N, float* __restrict__ out){
  __shared__ __align__(16) float Ws[32*16];
  int t = threadIdx.x;
  for(int i=t; i<32*16; i+=256) Ws[i] = W[i];
  __syncthreads();
  int row = blockIdx.x*256 + t;
  if(row >= N) return;
  const float4* xr = (const float4*)(x + (size_t)row*32);
  float acc[16];
  #pragma unroll
  for(int j=0;j<16;j++) acc[j]=0.f;
  #pragma unroll
  for(int k4=0;k4<8;k4++){
    float4 v = xr[k4];
    float vv[4] = {v.x, v.y, v.z, v.w};
    #pragma unroll
    for(int kk=0;kk<4;kk++){
      float h = vv[kk];
      const float* wr = &Ws[(k4*4+kk)*16];
      #pragma unroll
      for(int j=0;j<16;j++) acc[j] += h*wr[j];
    }
  }
  float4* o = (float4*)(out + (size_t)row*16);
  o[0] = make_float4(acc[0],acc[1],acc[2],acc[3]);
  o[1] = make_float4(acc[4],acc[5],acc[6],acc[7]);
  o[2] = make_float4(acc[8],acc[9],acc[10],acc[11]);
  o[3] = make_float4(acc[12],acc[13],acc[14],acc[15]);
}

// ---------------- tiled GEMM: [N,CIN] @ [CIN,64] -> [N,64] ----------------
// 128-row tiles; h staged transposed in LDS (pad 132 keeps float4 alignment);
// thread = 8 rows x 4 cols.
template<int CIN>
__global__ __launch_bounds__(256) void k_gemm_t(const float* __restrict__ h,
                                                const float* __restrict__ W,
                                                int N, float* __restrict__ out){
  __shared__ __align__(16) float hT[CIN][132];
  __shared__ __align__(16) float Ws[CIN*64];
  int t = threadIdx.x;
  int rowbase = blockIdx.x*128;
  #pragma unroll
  for(int i=0;i<CIN/2;i++){
    int idx = i*256 + t;
    int k = idx & (CIN-1);
    int r = idx / CIN;
    int row = rowbase + r;
    hT[k][r] = (row < N) ? h[(size_t)row*CIN + k] : 0.f;
  }
  for(int i=t; i<CIN*64; i+=256) Ws[i] = W[i];
  __syncthreads();

  int cg = t & 15, rg = t >> 4;   // 16 col-groups x 16 row-groups
  float acc[8][4];
  #pragma unroll
  for(int r=0;r<8;r++)
    #pragma unroll
    for(int c=0;c<4;c++) acc[r][c]=0.f;

  for(int k=0;k<CIN;k++){
    float4 a0 = *(const float4*)&hT[k][rg*8];
    float4 a1 = *(const float4*)&hT[k][rg*8+4];
    float4 wv = *(const float4*)&Ws[k*64 + cg*4];
    float ar[8] = {a0.x,a0.y,a0.z,a0.w,a1.x,a1.y,a1.z,a1.w};
    float wc[4] = {wv.x,wv.y,wv.z,wv.w};
    #pragma unroll
    for(int r=0;r<8;r++)
      #pragma unroll
      for(int c=0;c<4;c++)
        acc[r][c] += ar[r]*wc[c];
  }
  #pragma unroll
  for(int r=0;r<8;r++){
    int row = rowbase + rg*8 + r;
    if(row < N)
      *(float4*)(out + (size_t)row*64 + cg*4) =
        make_float4(acc[r][0],acc[r][1],acc[r][2],acc[r][3]);
  }
}

// ---------------- self-loop init: A = B*dis^2 + bias ----------------
template<int C>
__global__ void k_self(const float* __restrict__ B, const float* __restrict__ dis,
                       const float* __restrict__ bias, int N, float* __restrict__ A){
  constexpr int GP = C/4;
  int idx = blockIdx.x*256 + threadIdx.x;
  if(idx >= N*GP) return;
  int n = idx / GP, g = idx % GP;
  float d = dis[n], d2 = d*d;
  float4 v = *(const float4*)(B + (size_t)n*C + g*4);
  float4 bb = *(const float4*)(bias + g*4);
  v.x = v.x*d2 + bb.x; v.y = v.y*d2 + bb.y;
  v.z = v.z*d2 + bb.z; v.w = v.w*d2 + bb.w;
  *(float4*)(A + (size_t)n*C + g*4) = v;
}

// ---------------- edge scatter: A[dst] += B[src]*dis[src]*dis[dst] ----------------
template<int C>
__global__ void k_scatter(const int* __restrict__ src, const int* __restrict__ dst,
                          const float* __restrict__ dis, const float* __restrict__ B,
                          int E, float* __restrict__ A){
  constexpr int GP = C/4;
  int idx = blockIdx.x*256 + threadIdx.x;
  if(idx >= E*GP) return;
  int e = idx / GP, g = idx % GP;
  int s = src[e], d = dst[e];
  float coef = dis[s]*dis[d];
  float4 v = *(const float4*)(B + (size_t)s*C + g*4);
  float* o = A + (size_t)d*C + g*4;
  unsafeAtomicAdd(o+0, v.x*coef);
  unsafeAtomicAdd(o+1, v.y*coef);
  unsafeAtomicAdd(o+2, v.z*coef);
  unsafeAtomicAdd(o+3, v.w*coef);
}

// ---------------- tanh in place + per-column partial sums ----------------
template<int C>
__global__ void k_tanh_stats(float* __restrict__ A, int N, float* __restrict__ partials){
  int t = threadIdx.x;
  int total = N*C;
  int stride = STATS_BLOCKS*256;
  float s = 0.f, q = 0.f;
  for(int idx = blockIdx.x*256 + t; idx < total; idx += stride){
    float v = tanhf(A[idx]);
    A[idx] = v;
    s += v; q += v*v;
  }
  __shared__ float ls[256], lq[256];
  ls[t]=s; lq[t]=q;
  __syncthreads();
  if(t < C){
    float S=0.f, Q=0.f;
    #pragma unroll
    for(int g=0; g<256/C; g++){ S += ls[g*C+t]; Q += lq[g*C+t]; }
    partials[blockIdx.x*2*C + t]     = S;
    partials[blockIdx.x*2*C + C + t] = Q;
  }
}

// ---------------- finalize BN: scale/shift per column ----------------
template<int C>
__global__ void k_bn_final(const float* __restrict__ partials,
                           const float* __restrict__ gw, const float* __restrict__ be,
                           float invN, float* __restrict__ stats){
  constexpr int CH = 1024/C;
  int t = threadIdx.x;
  int c = t % C, ch = t / C;
  float S=0.f, Q=0.f;
  for(int b=ch; b<STATS_BLOCKS; b+=CH){
    S += partials[b*2*C + c];
    Q += partials[b*2*C + C + c];
  }
  __shared__ float fs[1024], fq[1024];
  fs[t]=S; fq[t]=Q;
  __syncthreads();
  if(t < C){
    float St=fs[t], Qt=fq[t];
    for(int g=1; g<CH; g++){ St += fs[g*C+t]; Qt += fq[g*C+t]; }
    float m = St*invN;
    float var = fmaxf(Qt*invN - m*m, 0.f);
    float inv = rsqrtf(var + EPSV);
    float sc = gw[t]*inv;
    stats[t]   = sc;
    stats[C+t] = be[t] - m*sc;
  }
}

// ---------------- apply BN: A = A*scale + shift ----------------
template<int C>
__global__ void k_bn_apply(float* __restrict__ A, int N, const float* __restrict__ stats){
  constexpr int GP = C/4;
  int idx = blockIdx.x*256 + threadIdx.x;
  if(idx >= N*GP) return;
  int g = idx % GP;
  float4 v  = *(const float4*)(A + (size_t)idx*4);
  float4 sc = *(const float4*)(stats + g*4);
  float4 sh = *(const float4*)(stats + C + g*4);
  v.x = v.x*sc.x + sh.x; v.y = v.y*sc.y + sh.y;
  v.z = v.z*sc.z + sh.z; v.w = v.w*sc.w + sh.w;
  *(float4*)(A + (size_t)idx*4) = v;
}

// ---------------- tanh only (layer 3) ----------------
__global__ void k_tanh(float* __restrict__ A, int total4){
  int idx = blockIdx.x*256 + threadIdx.x;
  if(idx >= total4) return;
  float4 v = *(const float4*)(A + (size_t)idx*4);
  v.x = tanhf(v.x); v.y = tanhf(v.y); v.z = tanhf(v.z); v.w = tanhf(v.w);
  *(float4*)(A + (size_t)idx*4) = v;
}

// ---------------- mean-pool per graph + linear head (fused) ----------------
__global__ __launch_bounds__(256) void k_pool(const float* __restrict__ A,
                                              const int* __restrict__ batch, int N,
                                              const float* __restrict__ Wc,
                                              const float* __restrict__ bc,
                                              float* __restrict__ out){
  int gId = blockIdx.x;
  int t = threadIdx.x;
  // lower_bound on sorted batch
  int lo=0, hi=N;
  while(lo<hi){ int mid=(lo+hi)>>1; if(batch[mid] < gId) lo=mid+1; else hi=mid; }
  int start = lo;
  lo=start; hi=N;
  while(lo<hi){ int mid=(lo+hi)>>1; if(batch[mid] < gId+1) lo=mid+1; else hi=mid; }
  int end = lo;

  int c = t & 63, rg = t >> 6;
  float s = 0.f;
  for(int r = start+rg; r < end; r += 4) s += A[(size_t)r*64 + c];
  __shared__ float ls[256];
  ls[t] = s;
  __syncthreads();
  if(t < 64){
    float tot = ls[t] + ls[64+t] + ls[128+t] + ls[192+t];
    float cnt = (float)(end - start);
    float mean = tot / fmaxf(cnt, 1.0f);
    float v = mean * Wc[t];
    #pragma unroll
    for(int o=32; o>0; o>>=1) v += __shfl_down(v, o, 64);
    if(t == 0) out[gId] = v + bc[0];
  }
}

// ---------------- host launch ----------------
extern "C" void kernel_launch(void* const* d_in, const int* in_sizes, int n_in,
                              void* d_out, int out_size, void* d_ws, size_t ws_size,
                              hipStream_t stream) {
  const float* x     = (const float*)d_in[0];
  const int*   ei    = (const int*)d_in[1];
  const int*   batch = (const int*)d_in[2];
  const float* W1 = (const float*)d_in[3];
  const float* b1 = (const float*)d_in[4];
  const float* g1 = (const float*)d_in[5];
  const float* be1= (const float*)d_in[6];
  const float* W2 = (const float*)d_in[7];
  const float* b2 = (const float*)d_in[8];
  const float* g2 = (const float*)d_in[9];
  const float* be2= (const float*)d_in[10];
  const float* W3 = (const float*)d_in[11];
  const float* b3 = (const float*)d_in[12];
  const float* Wc = (const float*)d_in[13];
  const float* bc = (const float*)d_in[14];

  int N = in_sizes[2];
  int E = in_sizes[1] / 2;
  int G = out_size;
  const int* srcp = ei;
  const int* dstp = ei + E;
  float* out = (float*)d_out;

  char* w = (char*)d_ws;
  float* A        = (float*)w; w += (size_t)N*64*4;
  float* Bb       = (float*)w; w += (size_t)N*64*4;
  float* dis      = (float*)w; w += (size_t)N*4;
  int*   degc     = (int*)w;   w += (size_t)N*4;
  float* partials = (float*)w; w += (size_t)STATS_BLOCKS*128*4;
  float* stats    = (float*)w; w += 512;

  auto cdiv = [](long long a, long long b){ return (int)((a+b-1)/b); };

  hipMemsetAsync(degc, 0, (size_t)N*4, stream);
  k_deg<<<cdiv(E,256),256,0,stream>>>(dstp, E, degc);
  k_dis<<<cdiv(N,256),256,0,stream>>>(degc, N, dis);

  // ---- Layer 1: 32 -> 16 ----
  k_gemm1<<<cdiv(N,256),256,0,stream>>>(x, W1, N, Bb);
  k_self<16><<<cdiv((long long)N*4,256),256,0,stream>>>(Bb, dis, b1, N, A);
  k_scatter<16><<<cdiv((long long)E*4,256),256,0,stream>>>(srcp, dstp, dis, Bb, E, A);
  k_tanh_stats<16><<<STATS_BLOCKS,256,0,stream>>>(A, N, partials);
  k_bn_final<16><<<1,1024,0,stream>>>(partials, g1, be1, 1.0f/N, stats);
  k_bn_apply<16><<<cdiv((long long)N*4,256),256,0,stream>>>(A, N, stats);

  // ---- Layer 2: 16 -> 64 ----
  k_gemm_t<16><<<cdiv(N,128),256,0,stream>>>(A, W2, N, Bb);
  k_self<64><<<cdiv((long long)N*16,256),256,0,stream>>>(Bb, dis, b2, N, A);
  k_scatter<64><<<cdiv((long long)E*16,256),256,0,stream>>>(srcp, dstp, dis, Bb, E, A);
  k_tanh_stats<64><<<STATS_BLOCKS,256,0,stream>>>(A, N, partials);
  k_bn_final<64><<<1,1024,0,stream>>>(partials, g2, be2, 1.0f/N, stats);
  k_bn_apply<64><<<cdiv((long long)N*16,256),256,0,stream>>>(A, N, stats);

  // ---- Layer 3: 64 -> 64 ----
  k_gemm_t<64><<<cdiv(N,128),256,0,stream>>>(A, W3, N, Bb);
  k_self<64><<<cdiv((long long)N*16,256),256,0,stream>>>(Bb, dis, b3, N, A);
  k_scatter<64><<<cdiv((long long)E*16,256),256,0,stream>>>(srcp, dstp, dis, Bb, E, A);
  k_tanh<<<cdiv((long long)N*16,256),256,0,stream>>>(A, N*16);

  // ---- Pool + head ----
  k_pool<<<G,256,0,stream>>>(A, batch, N, Wc, bc, out);
}

// Round 2
// 672.160 us; speedup vs baseline: 4.8578x; 4.8578x over previous
//
#include <hip/hip_runtime.h>

#define EPSV 1e-5f
#define STATS_BLOCKS 512

// ---------------- degree histogram ----------------
__global__ void k_deg(const int* __restrict__ dst, int E, int* __restrict__ degc){
  int i = blockIdx.x*blockDim.x + threadIdx.x;
  if(i < E) atomicAdd(&degc[dst[i]], 1);
}

__global__ void k_dis(const int* __restrict__ degc, int N, float* __restrict__ dis){
  int i = blockIdx.x*blockDim.x + threadIdx.x;
  if(i < N) dis[i] = rsqrtf((float)degc[i] + 1.0f);
}

// ---------------- single-block exclusive scan -> row_ptr, cursor ----------------
__global__ __launch_bounds__(1024) void k_scan(const int* __restrict__ degc, int N,
                                               int* __restrict__ rp, int* __restrict__ cursor){
  __shared__ int ps[1024];
  int t = threadIdx.x;
  int chunk = (N + 1023)/1024;
  int lo = t*chunk, hi = lo+chunk < N ? lo+chunk : N;
  if(lo > N) lo = N;
  int s = 0;
  for(int i=lo;i<hi;i++) s += degc[i];
  ps[t] = s;
  __syncthreads();
  // inclusive Hillis-Steele scan
  for(int off=1; off<1024; off<<=1){
    int v = (t>=off) ? ps[t-off] : 0;
    __syncthreads();
    ps[t] += v;
    __syncthreads();
  }
  int run = (t==0) ? 0 : ps[t-1];
  for(int i=lo;i<hi;i++){
    rp[i] = run; cursor[i] = run;
    run += degc[i];
  }
  if(t == 1023) rp[N] = run;
}

// ---------------- CSR fill (by dst) ----------------
__global__ void k_fill(const int* __restrict__ src, const int* __restrict__ dst,
                       const float* __restrict__ dis, int E,
                       int* cursor, int* __restrict__ csr_src, float* __restrict__ csr_w){
  int e = blockIdx.x*256 + threadIdx.x;
  if(e >= E) return;
  int s = src[e], d = dst[e];
  int pos = atomicAdd(&cursor[d], 1);
  csr_src[pos] = s;
  csr_w[pos] = dis[s]*dis[d];
}

// ---------------- layer-1 GEMM: [N,32] @ [32,16] -> [N,16] ----------------
__global__ __launch_bounds__(256) void k_gemm1(const float* __restrict__ x,
                                               const float* __restrict__ W,
                                               int N, float* __restrict__ out){
  __shared__ __align__(16) float Ws[32*16];
  int t = threadIdx.x;
  for(int i=t; i<32*16; i+=256) Ws[i] = W[i];
  __syncthreads();
  int row = blockIdx.x*256 + t;
  if(row >= N) return;
  const float4* xr = (const float4*)(x + (size_t)row*32);
  float acc[16];
  #pragma unroll
  for(int j=0;j<16;j++) acc[j]=0.f;
  #pragma unroll
  for(int k4=0;k4<8;k4++){
    float4 v = xr[k4];
    float vv[4] = {v.x, v.y, v.z, v.w};
    #pragma unroll
    for(int kk=0;kk<4;kk++){
      float h = vv[kk];
      const float* wr = &Ws[(k4*4+kk)*16];
      #pragma unroll
      for(int j=0;j<16;j++) acc[j] += h*wr[j];
    }
  }
  float4* o = (float4*)(out + (size_t)row*16);
  o[0] = make_float4(acc[0],acc[1],acc[2],acc[3]);
  o[1] = make_float4(acc[4],acc[5],acc[6],acc[7]);
  o[2] = make_float4(acc[8],acc[9],acc[10],acc[11]);
  o[3] = make_float4(acc[12],acc[13],acc[14],acc[15]);
}

// ---------------- tiled GEMM: [N,CIN] @ [CIN,64] -> [N,64] ----------------
template<int CIN>
__global__ __launch_bounds__(256) void k_gemm_t(const float* __restrict__ h,
                                                const float* __restrict__ W,
                                                int N, float* __restrict__ out){
  __shared__ __align__(16) float hT[CIN][132];
  __shared__ __align__(16) float Ws[CIN*64];
  int t = threadIdx.x;
  int rowbase = blockIdx.x*128;
  #pragma unroll
  for(int i=0;i<CIN/2;i++){
    int idx = i*256 + t;
    int k = idx & (CIN-1);
    int r = idx / CIN;
    int row = rowbase + r;
    hT[k][r] = (row < N) ? h[(size_t)row*CIN + k] : 0.f;
  }
  for(int i=t; i<CIN*64; i+=256) Ws[i] = W[i];
  __syncthreads();

  int cg = t & 15, rg = t >> 4;
  float acc[8][4];
  #pragma unroll
  for(int r=0;r<8;r++)
    #pragma unroll
    for(int c=0;c<4;c++) acc[r][c]=0.f;

  for(int k=0;k<CIN;k++){
    float4 a0 = *(const float4*)&hT[k][rg*8];
    float4 a1 = *(const float4*)&hT[k][rg*8+4];
    float4 wv = *(const float4*)&Ws[k*64 + cg*4];
    float ar[8] = {a0.x,a0.y,a0.z,a0.w,a1.x,a1.y,a1.z,a1.w};
    float wc[4] = {wv.x,wv.y,wv.z,wv.w};
    #pragma unroll
    for(int r=0;r<8;r++)
      #pragma unroll
      for(int c=0;c<4;c++)
        acc[r][c] += ar[r]*wc[c];
  }
  #pragma unroll
  for(int r=0;r<8;r++){
    int row = rowbase + rg*8 + r;
    if(row < N)
      *(float4*)(out + (size_t)row*64 + cg*4) =
        make_float4(acc[r][0],acc[r][1],acc[r][2],acc[r][3]);
  }
}

// ---------------- gather aggregation: A = tanh(self + sum_edges + bias) ----------------
// thread = (node, 4-col group); 16 consecutive lanes read one 256B source row coalesced.
template<int C>
__global__ __launch_bounds__(256) void k_gather(const int* __restrict__ rp,
    const int* __restrict__ csr_src, const float* __restrict__ csr_w,
    const float* __restrict__ dis, const float* __restrict__ B,
    const float* __restrict__ bias, int N, float* __restrict__ A){
  constexpr int GP = C/4;
  int idx = blockIdx.x*256 + threadIdx.x;
  if(idx >= N*GP) return;
  int n = idx / GP, g = idx % GP;
  int beg = rp[n], end = rp[n+1];
  float d = dis[n], d2 = d*d;
  float4 v  = *(const float4*)(B + (size_t)n*C + g*4);
  float4 bb = *(const float4*)(bias + g*4);
  float ax = v.x*d2 + bb.x, ay = v.y*d2 + bb.y;
  float az = v.z*d2 + bb.z, aw = v.w*d2 + bb.w;
  float bx = 0.f, by = 0.f, bz = 0.f, bw = 0.f;

  int j = beg;
  for(; j+1 < end; j += 2){
    int   s0 = csr_src[j],   s1 = csr_src[j+1];
    float w0 = csr_w[j],     w1 = csr_w[j+1];
    float4 u0 = *(const float4*)(B + (size_t)s0*C + g*4);
    float4 u1 = *(const float4*)(B + (size_t)s1*C + g*4);
    ax += u0.x*w0; ay += u0.y*w0; az += u0.z*w0; aw += u0.w*w0;
    bx += u1.x*w1; by += u1.y*w1; bz += u1.z*w1; bw += u1.w*w1;
  }
  if(j < end){
    int s0 = csr_src[j];
    float w0 = csr_w[j];
    float4 u0 = *(const float4*)(B + (size_t)s0*C + g*4);
    ax += u0.x*w0; ay += u0.y*w0; az += u0.z*w0; aw += u0.w*w0;
  }
  float4 o;
  o.x = tanhf(ax + bx); o.y = tanhf(ay + by);
  o.z = tanhf(az + bz); o.w = tanhf(aw + bw);
  *(float4*)(A + (size_t)n*C + g*4) = o;
}

// ---------------- per-column partial sums (read-only) ----------------
template<int C>
__global__ void k_stats(const float* __restrict__ A, int N, float* __restrict__ partials){
  int t = threadIdx.x;
  int total = N*C;
  int stride = STATS_BLOCKS*256;
  float s = 0.f, q = 0.f;
  for(int idx = blockIdx.x*256 + t; idx < total; idx += stride){
    float v = A[idx];
    s += v; q += v*v;
  }
  __shared__ float ls[256], lq[256];
  ls[t]=s; lq[t]=q;
  __syncthreads();
  if(t < C){
    float S=0.f, Q=0.f;
    #pragma unroll
    for(int g=0; g<256/C; g++){ S += ls[g*C+t]; Q += lq[g*C+t]; }
    partials[blockIdx.x*2*C + t]     = S;
    partials[blockIdx.x*2*C + C + t] = Q;
  }
}

// ---------------- finalize BN scale/shift ----------------
template<int C>
__global__ void k_bn_final(const float* __restrict__ partials,
                           const float* __restrict__ gw, const float* __restrict__ be,
                           float invN, float* __restrict__ stats){
  constexpr int CH = 1024/C;
  int t = threadIdx.x;
  int c = t % C, ch = t / C;
  float S=0.f, Q=0.f;
  for(int b=ch; b<STATS_BLOCKS; b+=CH){
    S += partials[b*2*C + c];
    Q += partials[b*2*C + C + c];
  }
  __shared__ float fs[1024], fq[1024];
  fs[t]=S; fq[t]=Q;
  __syncthreads();
  if(t < C){
    float St=fs[t], Qt=fq[t];
    for(int g=1; g<CH; g++){ St += fs[g*C+t]; Qt += fq[g*C+t]; }
    float m = St*invN;
    float var = fmaxf(Qt*invN - m*m, 0.f);
    float inv = rsqrtf(var + EPSV);
    float sc = gw[t]*inv;
    stats[t]   = sc;
    stats[C+t] = be[t] - m*sc;
  }
}

// ---------------- apply BN ----------------
template<int C>
__global__ void k_bn_apply(float* __restrict__ A, int N, const float* __restrict__ stats){
  constexpr int GP = C/4;
  int idx = blockIdx.x*256 + threadIdx.x;
  if(idx >= N*GP) return;
  int g = idx % GP;
  float4 v  = *(const float4*)(A + (size_t)idx*4);
  float4 sc = *(const float4*)(stats + g*4);
  float4 sh = *(const float4*)(stats + C + g*4);
  v.x = v.x*sc.x + sh.x; v.y = v.y*sc.y + sh.y;
  v.z = v.z*sc.z + sh.z; v.w = v.w*sc.w + sh.w;
  *(float4*)(A + (size_t)idx*4) = v;
}

// ---------------- mean-pool per graph + linear head ----------------
__global__ __launch_bounds__(256) void k_pool(const float* __restrict__ A,
                                              const int* __restrict__ batch, int N,
                                              const float* __restrict__ Wc,
                                              const float* __restrict__ bc,
                                              float* __restrict__ out){
  int gId = blockIdx.x;
  int t = threadIdx.x;
  int lo=0, hi=N;
  while(lo<hi){ int mid=(lo+hi)>>1; if(batch[mid] < gId) lo=mid+1; else hi=mid; }
  int start = lo;
  lo=start; hi=N;
  while(lo<hi){ int mid=(lo+hi)>>1; if(batch[mid] < gId+1) lo=mid+1; else hi=mid; }
  int end = lo;

  int c = t & 63, rg = t >> 6;
  float s = 0.f;
  for(int r = start+rg; r < end; r += 4) s += A[(size_t)r*64 + c];
  __shared__ float ls[256];
  ls[t] = s;
  __syncthreads();
  if(t < 64){
    float tot = ls[t] + ls[64+t] + ls[128+t] + ls[192+t];
    float cnt = (float)(end - start);
    float mean = tot / fmaxf(cnt, 1.0f);
    float v = mean * Wc[t];
    #pragma unroll
    for(int o=32; o>0; o>>=1) v += __shfl_down(v, o, 64);
    if(t == 0) out[gId] = v + bc[0];
  }
}

// ---------------- host launch ----------------
extern "C" void kernel_launch(void* const* d_in, const int* in_sizes, int n_in,
                              void* d_out, int out_size, void* d_ws, size_t ws_size,
                              hipStream_t stream) {
  const float* x     = (const float*)d_in[0];
  const int*   ei    = (const int*)d_in[1];
  const int*   batch = (const int*)d_in[2];
  const float* W1 = (const float*)d_in[3];
  const float* b1 = (const float*)d_in[4];
  const float* g1 = (const float*)d_in[5];
  const float* be1= (const float*)d_in[6];
  const float* W2 = (const float*)d_in[7];
  const float* b2 = (const float*)d_in[8];
  const float* g2 = (const float*)d_in[9];
  const float* be2= (const float*)d_in[10];
  const float* W3 = (const float*)d_in[11];
  const float* b3 = (const float*)d_in[12];
  const float* Wc = (const float*)d_in[13];
  const float* bc = (const float*)d_in[14];

  int N = in_sizes[2];
  int E = in_sizes[1] / 2;
  int G = out_size;
  const int* srcp = ei;
  const int* dstp = ei + E;
  float* out = (float*)d_out;

  char* w = (char*)d_ws;
  float* A        = (float*)w; w += (size_t)N*64*4;
  float* Bb       = (float*)w; w += (size_t)N*64*4;
  float* dis      = (float*)w; w += (size_t)N*4;
  int*   degc     = (int*)w;   w += (size_t)N*4;
  int*   row_ptr  = (int*)w;   w += (size_t)(N+1)*4;
  int*   cursor   = (int*)w;   w += (size_t)N*4;
  int*   csr_src  = (int*)w;   w += (size_t)E*4;
  float* csr_w    = (float*)w; w += (size_t)E*4;
  float* partials = (float*)w; w += (size_t)STATS_BLOCKS*128*4;
  float* stats    = (float*)w; w += 512;

  auto cdiv = [](long long a, long long b){ return (int)((a+b-1)/b); };

  // ---- CSR build (once, reused by all 3 layers) ----
  hipMemsetAsync(degc, 0, (size_t)N*4, stream);
  k_deg<<<cdiv(E,256),256,0,stream>>>(dstp, E, degc);
  k_dis<<<cdiv(N,256),256,0,stream>>>(degc, N, dis);
  k_scan<<<1,1024,0,stream>>>(degc, N, row_ptr, cursor);
  k_fill<<<cdiv(E,256),256,0,stream>>>(srcp, dstp, dis, E, cursor, csr_src, csr_w);

  // ---- Layer 1: 32 -> 16 ----
  k_gemm1<<<cdiv(N,256),256,0,stream>>>(x, W1, N, Bb);
  k_gather<16><<<cdiv((long long)N*4,256),256,0,stream>>>(row_ptr, csr_src, csr_w, dis, Bb, b1, N, A);
  k_stats<16><<<STATS_BLOCKS,256,0,stream>>>(A, N, partials);
  k_bn_final<16><<<1,1024,0,stream>>>(partials, g1, be1, 1.0f/N, stats);
  k_bn_apply<16><<<cdiv((long long)N*4,256),256,0,stream>>>(A, N, stats);

  // ---- Layer 2: 16 -> 64 ----
  k_gemm_t<16><<<cdiv(N,128),256,0,stream>>>(A, W2, N, Bb);
  k_gather<64><<<cdiv((long long)N*16,256),256,0,stream>>>(row_ptr, csr_src, csr_w, dis, Bb, b2, N, A);
  k_stats<64><<<STATS_BLOCKS,256,0,stream>>>(A, N, partials);
  k_bn_final<64><<<1,1024,0,stream>>>(partials, g2, be2, 1.0f/N, stats);
  k_bn_apply<64><<<cdiv((long long)N*16,256),256,0,stream>>>(A, N, stats);

  // ---- Layer 3: 64 -> 64 ----
  k_gemm_t<64><<<cdiv(N,128),256,0,stream>>>(A, W3, N, Bb);
  k_gather<64><<<cdiv((long long)N*16,256),256,0,stream>>>(row_ptr, csr_src, csr_w, dis, Bb, b3, N, A);

  // ---- Pool + head ----
  k_pool<<<G,256,0,stream>>>(A, batch, N, Wc, bc, out);
}

// Round 3
// 458.226 us; speedup vs baseline: 7.1257x; 1.4669x over previous
//
#include <hip/hip_runtime.h>

#define EPSV 1e-5f
#define STATS_BLOCKS 512

// ---------------- degree histogram ----------------
__global__ void k_deg(const int* __restrict__ dst, int E, int* __restrict__ degc){
  int i = blockIdx.x*blockDim.x + threadIdx.x;
  if(i < E) atomicAdd(&degc[dst[i]], 1);
}

__global__ void k_dis(const int* __restrict__ degc, int N, float* __restrict__ dis){
  int i = blockIdx.x*blockDim.x + threadIdx.x;
  if(i < N) dis[i] = rsqrtf((float)degc[i] + 1.0f);
}

// ---------------- parallel scan: stage 1 (per-block exclusive scan) ----------------
__global__ __launch_bounds__(1024) void k_scan_local(const int* __restrict__ degc, int N,
                                                     int* __restrict__ loc, int* __restrict__ blk){
  __shared__ int ps[1024];
  int t = threadIdx.x;
  int i = blockIdx.x*1024 + t;
  int v = (i < N) ? degc[i] : 0;
  ps[t] = v;
  __syncthreads();
  for(int off=1; off<1024; off<<=1){
    int u = (t>=off) ? ps[t-off] : 0;
    __syncthreads();
    ps[t] += u;
    __syncthreads();
  }
  if(i < N) loc[i] = ps[t] - v;           // exclusive prefix within block
  if(t == 1023) blk[blockIdx.x] = ps[t];  // block total
}

// ---------------- parallel scan: stage 2 (scan block sums, single small block) ----------------
__global__ __launch_bounds__(1024) void k_scan_sums(int* __restrict__ blk, int nb,
                                                    int* __restrict__ totalOut){
  __shared__ int ps[1024];
  int t = threadIdx.x;
  int v = (t < nb) ? blk[t] : 0;
  ps[t] = v;
  __syncthreads();
  for(int off=1; off<1024; off<<=1){
    int u = (t>=off) ? ps[t-off] : 0;
    __syncthreads();
    ps[t] += u;
    __syncthreads();
  }
  if(t < nb) blk[t] = ps[t] - v;          // exclusive block offsets
  if(t == 1023) *totalOut = ps[t];        // rp[N] = E
}

// ---------------- parallel scan: stage 3 (add offsets, emit rp + cursor) ----------------
__global__ void k_scan_add(const int* __restrict__ loc, const int* __restrict__ blk, int N,
                           int* __restrict__ rp, int* __restrict__ cursor){
  int i = blockIdx.x*256 + threadIdx.x;
  if(i < N){
    int v = loc[i] + blk[i>>10];
    rp[i] = v; cursor[i] = v;
  }
}

// ---------------- CSR fill (by dst) ----------------
__global__ void k_fill(const int* __restrict__ src, const int* __restrict__ dst,
                       const float* __restrict__ dis, int E,
                       int* cursor, int* __restrict__ csr_src, float* __restrict__ csr_w){
  int e = blockIdx.x*256 + threadIdx.x;
  if(e >= E) return;
  int s = src[e], d = dst[e];
  int pos = atomicAdd(&cursor[d], 1);
  csr_src[pos] = s;
  csr_w[pos] = dis[s]*dis[d];
}

// ---------------- layer-1 GEMM: [N,32] @ [32,16] -> [N,16] ----------------
__global__ __launch_bounds__(256) void k_gemm1(const float* __restrict__ x,
                                               const float* __restrict__ W,
                                               int N, float* __restrict__ out){
  __shared__ __align__(16) float Ws[32*16];
  int t = threadIdx.x;
  for(int i=t; i<32*16; i+=256) Ws[i] = W[i];
  __syncthreads();
  int row = blockIdx.x*256 + t;
  if(row >= N) return;
  const float4* xr = (const float4*)(x + (size_t)row*32);
  float acc[16];
  #pragma unroll
  for(int j=0;j<16;j++) acc[j]=0.f;
  #pragma unroll
  for(int k4=0;k4<8;k4++){
    float4 v = xr[k4];
    float vv[4] = {v.x, v.y, v.z, v.w};
    #pragma unroll
    for(int kk=0;kk<4;kk++){
      float h = vv[kk];
      const float* wr = &Ws[(k4*4+kk)*16];
      #pragma unroll
      for(int j=0;j<16;j++) acc[j] += h*wr[j];
    }
  }
  float4* o = (float4*)(out + (size_t)row*16);
  o[0] = make_float4(acc[0],acc[1],acc[2],acc[3]);
  o[1] = make_float4(acc[4],acc[5],acc[6],acc[7]);
  o[2] = make_float4(acc[8],acc[9],acc[10],acc[11]);
  o[3] = make_float4(acc[12],acc[13],acc[14],acc[15]);
}

// ---------------- tiled GEMM: [N,CIN] @ [CIN,64] -> [N,64] ----------------
template<int CIN>
__global__ __launch_bounds__(256) void k_gemm_t(const float* __restrict__ h,
                                                const float* __restrict__ W,
                                                int N, float* __restrict__ out){
  __shared__ __align__(16) float hT[CIN][132];
  __shared__ __align__(16) float Ws[CIN*64];
  int t = threadIdx.x;
  int rowbase = blockIdx.x*128;
  #pragma unroll
  for(int i=0;i<CIN/2;i++){
    int idx = i*256 + t;
    int k = idx & (CIN-1);
    int r = idx / CIN;
    int row = rowbase + r;
    hT[k][r] = (row < N) ? h[(size_t)row*CIN + k] : 0.f;
  }
  for(int i=t; i<CIN*64; i+=256) Ws[i] = W[i];
  __syncthreads();

  int cg = t & 15, rg = t >> 4;
  float acc[8][4];
  #pragma unroll
  for(int r=0;r<8;r++)
    #pragma unroll
    for(int c=0;c<4;c++) acc[r][c]=0.f;

  for(int k=0;k<CIN;k++){
    float4 a0 = *(const float4*)&hT[k][rg*8];
    float4 a1 = *(const float4*)&hT[k][rg*8+4];
    float4 wv = *(const float4*)&Ws[k*64 + cg*4];
    float ar[8] = {a0.x,a0.y,a0.z,a0.w,a1.x,a1.y,a1.z,a1.w};
    float wc[4] = {wv.x,wv.y,wv.z,wv.w};
    #pragma unroll
    for(int r=0;r<8;r++)
      #pragma unroll
      for(int c=0;c<4;c++)
        acc[r][c] += ar[r]*wc[c];
  }
  #pragma unroll
  for(int r=0;r<8;r++){
    int row = rowbase + rg*8 + r;
    if(row < N)
      *(float4*)(out + (size_t)row*64 + cg*4) =
        make_float4(acc[r][0],acc[r][1],acc[r][2],acc[r][3]);
  }
}

// ---------------- gather aggregation: A = tanh(self + sum_edges + bias) ----------------
template<int C>
__global__ __launch_bounds__(256) void k_gather(const int* __restrict__ rp,
    const int* __restrict__ csr_src, const float* __restrict__ csr_w,
    const float* __restrict__ dis, const float* __restrict__ B,
    const float* __restrict__ bias, int N, float* __restrict__ A){
  constexpr int GP = C/4;
  int idx = blockIdx.x*256 + threadIdx.x;
  if(idx >= N*GP) return;
  int n = idx / GP, g = idx % GP;
  int beg = rp[n], end = rp[n+1];
  float d = dis[n], d2 = d*d;
  float4 v  = *(const float4*)(B + (size_t)n*C + g*4);
  float4 bb = *(const float4*)(bias + g*4);
  float ax = v.x*d2 + bb.x, ay = v.y*d2 + bb.y;
  float az = v.z*d2 + bb.z, aw = v.w*d2 + bb.w;
  float bx = 0.f, by = 0.f, bz = 0.f, bw = 0.f;

  int j = beg;
  for(; j+1 < end; j += 2){
    int   s0 = csr_src[j],   s1 = csr_src[j+1];
    float w0 = csr_w[j],     w1 = csr_w[j+1];
    float4 u0 = *(const float4*)(B + (size_t)s0*C + g*4);
    float4 u1 = *(const float4*)(B + (size_t)s1*C + g*4);
    ax += u0.x*w0; ay += u0.y*w0; az += u0.z*w0; aw += u0.w*w0;
    bx += u1.x*w1; by += u1.y*w1; bz += u1.z*w1; bw += u1.w*w1;
  }
  if(j < end){
    int s0 = csr_src[j];
    float w0 = csr_w[j];
    float4 u0 = *(const float4*)(B + (size_t)s0*C + g*4);
    ax += u0.x*w0; ay += u0.y*w0; az += u0.z*w0; aw += u0.w*w0;
  }
  float4 o;
  o.x = tanhf(ax + bx); o.y = tanhf(ay + by);
  o.z = tanhf(az + bz); o.w = tanhf(aw + bw);
  *(float4*)(A + (size_t)n*C + g*4) = o;
}

// ---------------- per-column partial sums (read-only) ----------------
template<int C>
__global__ void k_stats(const float* __restrict__ A, int N, float* __restrict__ partials){
  int t = threadIdx.x;
  int total = N*C;
  int stride = STATS_BLOCKS*256;
  float s = 0.f, q = 0.f;
  for(int idx = blockIdx.x*256 + t; idx < total; idx += stride){
    float v = A[idx];
    s += v; q += v*v;
  }
  __shared__ float ls[256], lq[256];
  ls[t]=s; lq[t]=q;
  __syncthreads();
  if(t < C){
    float S=0.f, Q=0.f;
    #pragma unroll
    for(int g=0; g<256/C; g++){ S += ls[g*C+t]; Q += lq[g*C+t]; }
    partials[blockIdx.x*2*C + t]     = S;
    partials[blockIdx.x*2*C + C + t] = Q;
  }
}

// ---------------- finalize BN scale/shift ----------------
template<int C>
__global__ void k_bn_final(const float* __restrict__ partials,
                           const float* __restrict__ gw, const float* __restrict__ be,
                           float invN, float* __restrict__ stats){
  constexpr int CH = 1024/C;
  int t = threadIdx.x;
  int c = t % C, ch = t / C;
  float S=0.f, Q=0.f;
  for(int b=ch; b<STATS_BLOCKS; b+=CH){
    S += partials[b*2*C + c];
    Q += partials[b*2*C + C + c];
  }
  __shared__ float fs[1024], fq[1024];
  fs[t]=S; fq[t]=Q;
  __syncthreads();
  if(t < C){
    float St=fs[t], Qt=fq[t];
    for(int g=1; g<CH; g++){ St += fs[g*C+t]; Qt += fq[g*C+t]; }
    float m = St*invN;
    float var = fmaxf(Qt*invN - m*m, 0.f);
    float inv = rsqrtf(var + EPSV);
    float sc = gw[t]*inv;
    stats[t]   = sc;
    stats[C+t] = be[t] - m*sc;
  }
}

// ---------------- apply BN ----------------
template<int C>
__global__ void k_bn_apply(float* __restrict__ A, int N, const float* __restrict__ stats){
  constexpr int GP = C/4;
  int idx = blockIdx.x*256 + threadIdx.x;
  if(idx >= N*GP) return;
  int g = idx % GP;
  float4 v  = *(const float4*)(A + (size_t)idx*4);
  float4 sc = *(const float4*)(stats + g*4);
  float4 sh = *(const float4*)(stats + C + g*4);
  v.x = v.x*sc.x + sh.x; v.y = v.y*sc.y + sh.y;
  v.z = v.z*sc.z + sh.z; v.w = v.w*sc.w + sh.w;
  *(float4*)(A + (size_t)idx*4) = v;
}

// ---------------- mean-pool per graph + linear head ----------------
__global__ __launch_bounds__(256) void k_pool(const float* __restrict__ A,
                                              const int* __restrict__ batch, int N,
                                              const float* __restrict__ Wc,
                                              const float* __restrict__ bc,
                                              float* __restrict__ out){
  int gId = blockIdx.x;
  int t = threadIdx.x;
  int lo=0, hi=N;
  while(lo<hi){ int mid=(lo+hi)>>1; if(batch[mid] < gId) lo=mid+1; else hi=mid; }
  int start = lo;
  lo=start; hi=N;
  while(lo<hi){ int mid=(lo+hi)>>1; if(batch[mid] < gId+1) lo=mid+1; else hi=mid; }
  int end = lo;

  int c = t & 63, rg = t >> 6;
  float s = 0.f;
  for(int r = start+rg; r < end; r += 4) s += A[(size_t)r*64 + c];
  __shared__ float ls[256];
  ls[t] = s;
  __syncthreads();
  if(t < 64){
    float tot = ls[t] + ls[64+t] + ls[128+t] + ls[192+t];
    float cnt = (float)(end - start);
    float mean = tot / fmaxf(cnt, 1.0f);
    float v = mean * Wc[t];
    #pragma unroll
    for(int o=32; o>0; o>>=1) v += __shfl_down(v, o, 64);
    if(t == 0) out[gId] = v + bc[0];
  }
}

// ---------------- host launch ----------------
extern "C" void kernel_launch(void* const* d_in, const int* in_sizes, int n_in,
                              void* d_out, int out_size, void* d_ws, size_t ws_size,
                              hipStream_t stream) {
  const float* x     = (const float*)d_in[0];
  const int*   ei    = (const int*)d_in[1];
  const int*   batch = (const int*)d_in[2];
  const float* W1 = (const float*)d_in[3];
  const float* b1 = (const float*)d_in[4];
  const float* g1 = (const float*)d_in[5];
  const float* be1= (const float*)d_in[6];
  const float* W2 = (const float*)d_in[7];
  const float* b2 = (const float*)d_in[8];
  const float* g2 = (const float*)d_in[9];
  const float* be2= (const float*)d_in[10];
  const float* W3 = (const float*)d_in[11];
  const float* b3 = (const float*)d_in[12];
  const float* Wc = (const float*)d_in[13];
  const float* bc = (const float*)d_in[14];

  int N = in_sizes[2];
  int E = in_sizes[1] / 2;
  int G = out_size;
  const int* srcp = ei;
  const int* dstp = ei + E;
  float* out = (float*)d_out;

  char* w = (char*)d_ws;
  float* A        = (float*)w; w += (size_t)N*64*4;
  float* Bb       = (float*)w; w += (size_t)N*64*4;
  float* dis      = (float*)w; w += (size_t)N*4;
  int*   degc     = (int*)w;   w += (size_t)N*4;
  int*   row_ptr  = (int*)w;   w += (size_t)(N+1)*4;
  int*   cursor   = (int*)w;   w += (size_t)N*4;
  int*   csr_src  = (int*)w;   w += (size_t)E*4;
  float* csr_w    = (float*)w; w += (size_t)E*4;
  int*   scan_loc = (int*)w;   w += (size_t)N*4;
  int*   scan_blk = (int*)w;   w += 1024*4;
  float* partials = (float*)w; w += (size_t)STATS_BLOCKS*128*4;
  float* stats    = (float*)w; w += 512;

  auto cdiv = [](long long a, long long b){ return (int)((a+b-1)/b); };
  int nb = cdiv(N, 1024);

  // ---- CSR build (once, reused by all 3 layers) ----
  hipMemsetAsync(degc, 0, (size_t)N*4, stream);
  k_deg<<<cdiv(E,256),256,0,stream>>>(dstp, E, degc);
  k_dis<<<cdiv(N,256),256,0,stream>>>(degc, N, dis);
  k_scan_local<<<nb,1024,0,stream>>>(degc, N, scan_loc, scan_blk);
  k_scan_sums<<<1,1024,0,stream>>>(scan_blk, nb, row_ptr + N);
  k_scan_add<<<cdiv(N,256),256,0,stream>>>(scan_loc, scan_blk, N, row_ptr, cursor);
  k_fill<<<cdiv(E,256),256,0,stream>>>(srcp, dstp, dis, E, cursor, csr_src, csr_w);

  // ---- Layer 1: 32 -> 16 ----
  k_gemm1<<<cdiv(N,256),256,0,stream>>>(x, W1, N, Bb);
  k_gather<16><<<cdiv((long long)N*4,256),256,0,stream>>>(row_ptr, csr_src, csr_w, dis, Bb, b1, N, A);
  k_stats<16><<<STATS_BLOCKS,256,0,stream>>>(A, N, partials);
  k_bn_final<16><<<1,1024,0,stream>>>(partials, g1, be1, 1.0f/N, stats);
  k_bn_apply<16><<<cdiv((long long)N*4,256),256,0,stream>>>(A, N, stats);

  // ---- Layer 2: 16 -> 64 ----
  k_gemm_t<16><<<cdiv(N,128),256,0,stream>>>(A, W2, N, Bb);
  k_gather<64><<<cdiv((long long)N*16,256),256,0,stream>>>(row_ptr, csr_src, csr_w, dis, Bb, b2, N, A);
  k_stats<64><<<STATS_BLOCKS,256,0,stream>>>(A, N, partials);
  k_bn_final<64><<<1,1024,0,stream>>>(partials, g2, be2, 1.0f/N, stats);
  k_bn_apply<64><<<cdiv((long long)N*16,256),256,0,stream>>>(A, N, stats);

  // ---- Layer 3: 64 -> 64 ----
  k_gemm_t<64><<<cdiv(N,128),256,0,stream>>>(A, W3, N, Bb);
  k_gather<64><<<cdiv((long long)N*16,256),256,0,stream>>>(row_ptr, csr_src, csr_w, dis, Bb, b3, N, A);

  // ---- Pool + head ----
  k_pool<<<G,256,0,stream>>>(A, batch, N, Wc, bc, out);
}